// Round 9
// baseline (259.659 us; speedup 1.0000x reference)
//
#include <hip/hip_runtime.h>
#include <hip/hip_bf16.h>

#define NS 256    // n_state
#define MO 128    // n_obs
#define BB 64     // batch
#define TT 1024   // time steps

typedef short s16x8 __attribute__((ext_vector_type(8)));
typedef float f32x4 __attribute__((ext_vector_type(4)));
typedef unsigned int uint;
typedef unsigned short ushort;

__device__ __forceinline__ ushort f2bf(float x) {
    uint u = __float_as_uint(x);
    uint r = (u + 0x7fffu + ((u >> 16) & 1u)) >> 16;
    return (ushort)r;
}
__device__ __forceinline__ float bf2f(ushort h) { return __uint_as_float(((uint)h) << 16); }

__device__ __forceinline__ uint pkbf2(float a, float b) {
    __hip_bfloat162 h = __float22bfloat162_rn(make_float2(a, b));
    union { __hip_bfloat162 b2; uint u; } cv;
    cv.b2 = h;
    return cv.u;
}

// split 8 fp32 into bf16 hi + lo fragments (element order = k ascending)
__device__ __forceinline__ void conv8(float4 f0, float4 f1, s16x8& vh, s16x8& vl) {
    uint h0 = pkbf2(f0.x, f0.y), h1 = pkbf2(f0.z, f0.w);
    uint h2 = pkbf2(f1.x, f1.y), h3 = pkbf2(f1.z, f1.w);
    float r0 = f0.x - __uint_as_float(h0 << 16);
    float r1 = f0.y - __uint_as_float(h0 & 0xffff0000u);
    float r2 = f0.z - __uint_as_float(h1 << 16);
    float r3 = f0.w - __uint_as_float(h1 & 0xffff0000u);
    float r4 = f1.x - __uint_as_float(h2 << 16);
    float r5 = f1.y - __uint_as_float(h2 & 0xffff0000u);
    float r6 = f1.z - __uint_as_float(h3 << 16);
    float r7 = f1.w - __uint_as_float(h3 & 0xffff0000u);
    uint l0 = pkbf2(r0, r1), l1 = pkbf2(r2, r3);
    uint l2 = pkbf2(r4, r5), l3 = pkbf2(r6, r7);
    union { uint u[4]; s16x8 v; } ch, cl;
    ch.u[0] = h0; ch.u[1] = h1; ch.u[2] = h2; ch.u[3] = h3;
    cl.u[0] = l0; cl.u[1] = l1; cl.u[2] = l2; cl.u[3] = l3;
    vh = ch.v; vl = cl.v;
}

__device__ __forceinline__ f32x4 mfma16(s16x8 a, s16x8 b, f32x4 c) {
    return __builtin_amdgcn_mfma_f32_16x16x32_bf16(a, b, c, 0, 0, 0);
}

// ---------------- setup kernels ----------------

// Fused: KH row i; AE[i][:] = A[i][:] - KH_row @ A; emit kah (K hi), aeh/ael.
__global__ void khaeff_kernel(const float* __restrict__ K, const float* __restrict__ H,
                              const float* __restrict__ A, float* __restrict__ AE,
                              ushort* __restrict__ kah,
                              ushort* __restrict__ aeh, ushort* __restrict__ ael) {
    int i = blockIdx.x, j = threadIdx.x;
    __shared__ float kl[MO];
    __shared__ float khr[NS];
    if (j < MO) {
        float v = K[i * MO + j];
        kl[j] = v;
        kah[i * MO + j] = f2bf(v);
    }
    __syncthreads();
    float acc = 0.f;
#pragma unroll 8
    for (int k = 0; k < MO; ++k) acc += kl[k] * H[k * NS + j];
    khr[j] = acc;
    __syncthreads();
    float ae = A[i * NS + j];
#pragma unroll 8
    for (int k = 0; k < NS; ++k) ae -= khr[k] * A[k * NS + j];
    AE[i * NS + j] = ae;
    ushort hi = f2bf(ae);
    aeh[i * NS + j] = hi;
    ael[i * NS + j] = f2bf(ae - bf2f(hi));
}

__global__ void matsq_kernel(const float* __restrict__ src, float* __restrict__ dst,
                             ushort* dh, ushort* dl) {
    int i = blockIdx.x, j = threadIdx.x;
    __shared__ float row[NS];
    row[j] = src[i * NS + j];
    __syncthreads();
    float acc = 0.f;
#pragma unroll 8
    for (int k = 0; k < NS; ++k) acc += row[k] * src[k * NS + j];
    dst[i * NS + j] = acc;
    if (dh) {
        ushort hi = f2bf(acc);
        dh[i * NS + j] = hi;
        dl[i * NS + j] = f2bf(acc - bf2f(hi));
    }
}

// ---------------- transposed MFMA serial scan, fused u = K@y^T ----------------
// D = M·x^T + K·y^T (transposed: M/K are MFMA A-operands, x/y are B-operands).
// y raw loads for step s+1 are issued BEFORE step s's x-chain (latency cover);
// conv + u-MFMAs run after the x-chain, off the serial dependence.
// __launch_bounds__(512, 1): 1 block/CU -> 256-reg cap, fragments fit unspilled.
// Hierarchy: 1024 = 16(step) x 8(chunk) x 8(group).
// MODE 0: grid 256, S=16, u from y, x0=0, end -> e_buf bf16 [b][64][NS].
// MODE 1: grid 32,  S=8,  u=e_buf[b][8g+s], x0=0, end -> e2 bf16 [b][8][NS].
// MODE 2: grid 4,   S=7,  u=e2[b][s], A^128, writes c2[b][s+1], c2[b][0]=0.
// MODE 3: grid 32,  S=7,  u=e_buf[b][8g+s], x0=c2[b][g], writes cbuf[b][8g+s+1],
//                          cbuf[b][8g]=x0.
// MODE 4: grid 256, S=16, u from y, x0=cbuf[b][cc], writes out (float4 direct).

template <int MODE>
__launch_bounds__(512, 1)
__global__ void scan16_kernel(const ushort* __restrict__ mh, const ushort* __restrict__ ml,
                              const ushort* __restrict__ kah,
                              const float* __restrict__ y_g, const ushort* __restrict__ ub,
                              const ushort* __restrict__ cin, float* outf,
                              ushort* __restrict__ wbf, ushort* __restrict__ ebf) {
    constexpr bool YF = (MODE == 0 || MODE == 4);
    constexpr int S = YF ? 16 : ((MODE == 1) ? 8 : 7);
    const int tid = threadIdx.x, blk = blockIdx.x;
    const int w = tid >> 6, l = tid & 63, lr = l & 15, lg = l >> 4;

    __shared__ ushort xh_s[2][16 * NS];
    __shared__ ushort xl_s[2][16 * NS];

    // matrix A-fragments (bf16 hi/lo): lane holds M[32w+16t+lr][32q+8lg..+7]
    s16x8 Bh[2][8], Bl[2][8];
#pragma unroll
    for (int t2 = 0; t2 < 2; ++t2) {
        int row = 16 * (2 * w + t2) + lr;
#pragma unroll
        for (int q = 0; q < 8; ++q) {
            int off = row * NS + 32 * q + 8 * lg;
            Bh[t2][q] = *(const s16x8*)(mh + off);
            Bl[t2][q] = *(const s16x8*)(ml + off);
        }
    }

    // K hi A-fragments (fused modes only)
    s16x8 KAh[2][4];
    if constexpr (YF) {
#pragma unroll
        for (int t2 = 0; t2 < 2; ++t2) {
            int row = 16 * (2 * w + t2) + lr;
#pragma unroll
            for (int q = 0; q < 4; ++q) {
                KAh[t2][q] = *(const s16x8*)(kah + row * MO + 32 * q + 8 * lg);
            }
        }
    }

    const int b0 = (blk & 3) * 16;   // modes 0/4
    const int cc = blk >> 2;         // modes 0/4 (0..63)

    // ---- init x state (buffer 0) + mode-specific init writes ----
#pragma unroll
    for (int jj = 0; jj < 8; ++jj) {
        int idx = jj * 512 + tid;  // 0..4095
        int m = idx >> 8, col = idx & 255;  // m = batch-column of tile
        ushort hu = 0;
        if constexpr (MODE == 3) {
            int rid = blk * 16 + m;
            int b = rid >> 3, g = rid & 7;
            hu = cin[((long)b * 8 + g) * NS + col];
            wbf[((long)b * 64 + 8 * g) * NS + col] = hu;  // cbuf[b][8g] = carry
        } else if constexpr (MODE == 4) {
            hu = cin[((long)(b0 + m) * 64 + cc) * NS + col];
        } else if constexpr (MODE == 2) {
            wbf[(long)(blk * 16 + m) * 8 * NS + col] = 0;  // c2[b][0] = 0
        }
        int si = (m * NS + col) ^ ((m & 7) << 3);
        xh_s[0][si] = hu;
        xl_s[0][si] = 0;
    }

    // state-column bases for this thread's two output tiles
    const int st0 = 32 * w + 4 * lg;
    const int st1 = st0 + 16;

    // y base (fused) / u base (bf16 carry modes)
    long ybase = 0, ubase = 0;
    if constexpr (YF) {
        ybase = ((long)(b0 + lr) * TT + cc * 16) * MO + 8 * lg;
    } else if constexpr (MODE == 1 || MODE == 3) {
        int rid = blk * 16 + lr;
        ubase = ((long)(rid >> 3) * 64 + 8 * (rid & 7)) * NS;
    } else {
        ubase = (long)(blk * 16 + lr) * 8 * NS;
    }

    auto ldu = [&](long off) -> f32x4 {
        uint2 v = *(const uint2*)(ub + off);
        return f32x4{__uint_as_float(v.x << 16), __uint_as_float(v.x & 0xffff0000u),
                     __uint_as_float(v.y << 16), __uint_as_float(v.y & 0xffff0000u)};
    };

    float4 yraw[8];
    auto load_y = [&](int s) {
#pragma unroll
        for (int q = 0; q < 4; ++q) {
            long off = ybase + (long)s * MO + 32 * q;
            yraw[2 * q] = *(const float4*)(y_g + off);
            yraw[2 * q + 1] = *(const float4*)(y_g + off + 4);
        }
    };

    // u(s) from yraw: u = K_hi·(y_hi + y_lo), 16 MFMAs
    auto compute_u = [&](f32x4& ua0, f32x4& ua1) {
        ua0 = f32x4{0.f, 0.f, 0.f, 0.f};
        ua1 = f32x4{0.f, 0.f, 0.f, 0.f};
#pragma unroll
        for (int q = 0; q < 4; ++q) {
            s16x8 yh, yl;
            conv8(yraw[2 * q], yraw[2 * q + 1], yh, yl);
            ua0 = mfma16(KAh[0][q], yh, ua0);
            ua0 = mfma16(KAh[0][q], yl, ua0);
            ua1 = mfma16(KAh[1][q], yh, ua1);
            ua1 = mfma16(KAh[1][q], yl, ua1);
        }
    };

    f32x4 up0, up1;
    if constexpr (YF) {
        load_y(0);
        compute_u(up0, up1);
    } else {
        up0 = ldu(ubase + st0);
        up1 = ldu(ubase + st1);
    }
    __syncthreads();

    for (int s = 0; s < S; ++s) {
        const int cur = s & 1, nxt = cur ^ 1;

        // issue raw y loads for s+1 FIRST (latency covered by the x-chain)
        if constexpr (YF) {
            if (s + 1 < S) load_y(s + 1);
        }

        f32x4 acc0 = up0, acc1 = up1;

        // serial x-chain: acc += M @ x
#pragma unroll
        for (int q = 0; q < 8; ++q) {
            int ridx = (lr * NS + 32 * q + 8 * lg) ^ ((lr & 7) << 3);
            s16x8 xh = *(const s16x8*)&xh_s[cur][ridx];
            s16x8 xl = *(const s16x8*)&xl_s[cur][ridx];
            acc0 = mfma16(Bh[0][q], xh, acc0);
            acc0 = mfma16(Bh[0][q], xl, acc0);
            acc0 = mfma16(Bl[0][q], xh, acc0);
            acc1 = mfma16(Bh[1][q], xh, acc1);
            acc1 = mfma16(Bh[1][q], xl, acc1);
            acc1 = mfma16(Bl[1][q], xh, acc1);
        }

        // u for next step (off the critical chain; y already in regs)
        if (s + 1 < S) {
            if constexpr (YF) {
                compute_u(up0, up1);
            } else {
                up0 = ldu(ubase + (long)(s + 1) * NS + st0);
                up1 = ldu(ubase + (long)(s + 1) * NS + st1);
            }
        }

        // packed bf16 of results (hi)
        uint h01a = pkbf2(acc0[0], acc0[1]), h23a = pkbf2(acc0[2], acc0[3]);
        uint h01b = pkbf2(acc1[0], acc1[1]), h23b = pkbf2(acc1[2], acc1[3]);

        // mode-specific global stores
        if constexpr (MODE == 2) {
            long wb = ((long)(blk * 16 + lr) * 8 + s + 1) * NS;
            *(uint2*)(wbf + wb + st0) = make_uint2(h01a, h23a);
            *(uint2*)(wbf + wb + st1) = make_uint2(h01b, h23b);
        } else if constexpr (MODE == 3) {
            int rid = blk * 16 + lr;
            long wb = ((long)(rid >> 3) * 64 + 8 * (rid & 7) + s + 1) * NS;
            *(uint2*)(wbf + wb + st0) = make_uint2(h01a, h23a);
            *(uint2*)(wbf + wb + st1) = make_uint2(h01b, h23b);
        } else if constexpr (MODE == 4) {
            long ob = ((long)(b0 + lr) * TT + cc * 16 + s) * NS;
            *(f32x4*)(outf + ob + st0) = acc0;
            *(f32x4*)(outf + ob + st1) = acc1;
        } else if constexpr (MODE == 0) {
            if (s == S - 1) {
                long eb = ((long)(b0 + lr) * 64 + cc) * NS;
                *(uint2*)(ebf + eb + st0) = make_uint2(h01a, h23a);
                *(uint2*)(ebf + eb + st1) = make_uint2(h01b, h23b);
            }
        } else if constexpr (MODE == 1) {
            if (s == S - 1) {
                int rid = blk * 16 + lr;
                long eb = ((long)(rid >> 3) * 8 + (rid & 7)) * NS;
                *(uint2*)(ebf + eb + st0) = make_uint2(h01a, h23a);
                *(uint2*)(ebf + eb + st1) = make_uint2(h01b, h23b);
            }
        }

        // write x[nxt]: vector b64 LDS writes under the (lr&7)<<3 XOR
        if (s + 1 < S) {
            float la0 = acc0[0] - __uint_as_float(h01a << 16);
            float la1 = acc0[1] - __uint_as_float(h01a & 0xffff0000u);
            float la2 = acc0[2] - __uint_as_float(h23a << 16);
            float la3 = acc0[3] - __uint_as_float(h23a & 0xffff0000u);
            float lb0 = acc1[0] - __uint_as_float(h01b << 16);
            float lb1 = acc1[1] - __uint_as_float(h01b & 0xffff0000u);
            float lb2 = acc1[2] - __uint_as_float(h23b << 16);
            float lb3 = acc1[3] - __uint_as_float(h23b & 0xffff0000u);
            int wi0 = lr * NS + (st0 ^ ((lr & 7) << 3));
            int wi1 = lr * NS + (st1 ^ ((lr & 7) << 3));
            *(uint2*)&xh_s[nxt][wi0] = make_uint2(h01a, h23a);
            *(uint2*)&xh_s[nxt][wi1] = make_uint2(h01b, h23b);
            *(uint2*)&xl_s[nxt][wi0] = make_uint2(pkbf2(la0, la1), pkbf2(la2, la3));
            *(uint2*)&xl_s[nxt][wi1] = make_uint2(pkbf2(lb0, lb1), pkbf2(lb2, lb3));
        }
        __syncthreads();
    }
}

// ---------------- launcher ----------------

extern "C" void kernel_launch(void* const* d_in, const int* in_sizes, int n_in,
                              void* d_out, int out_size, void* d_ws, size_t ws_size,
                              hipStream_t stream) {
    const float* y = (const float*)d_in[0];
    const float* A = (const float*)d_in[1];
    const float* H = (const float*)d_in[2];
    const float* K = (const float*)d_in[3];
    float* out = (float*)d_out;

    float* ws = (float*)d_ws;
    const long MAT = (long)NS * NS;  // 65536
    float* AE = ws + 0 * MAT;
    float* Ta = ws + 1 * MAT;
    float* Tb = ws + 2 * MAT;
    ushort* us = (ushort*)(ws + 3 * MAT);
    ushort* aeh = us;                       // 65536
    ushort* ael = aeh + MAT;                // 65536
    ushort* mh = ael + MAT;                 // A^16 hi
    ushort* ml = mh + MAT;
    ushort* m2h = ml + MAT;                 // A^128 hi
    ushort* m2l = m2h + MAT;
    ushort* kah = m2l + MAT;                // K hi: 32768
    ushort* e_buf = kah + (long)NS * MO;    // [64][64][256] = 1,048,576
    ushort* cbuf = e_buf + (long)BB * 64 * NS;
    ushort* e2 = cbuf + (long)BB * 64 * NS; // [64][8][256] = 131,072
    ushort* c2 = e2 + (long)BB * 8 * NS;

    khaeff_kernel<<<NS, NS, 0, stream>>>(K, H, A, AE, kah, aeh, ael);
    matsq_kernel<<<NS, NS, 0, stream>>>(AE, Ta, nullptr, nullptr);   // A^2
    matsq_kernel<<<NS, NS, 0, stream>>>(Ta, Tb, nullptr, nullptr);   // A^4
    matsq_kernel<<<NS, NS, 0, stream>>>(Tb, Ta, nullptr, nullptr);   // A^8
    matsq_kernel<<<NS, NS, 0, stream>>>(Ta, Tb, mh, ml);             // A^16 (+conv)
    matsq_kernel<<<NS, NS, 0, stream>>>(Tb, Ta, nullptr, nullptr);   // A^32
    matsq_kernel<<<NS, NS, 0, stream>>>(Ta, Tb, nullptr, nullptr);   // A^64
    matsq_kernel<<<NS, NS, 0, stream>>>(Tb, Ta, m2h, m2l);           // A^128 (+conv)

    scan16_kernel<0><<<256, 512, 0, stream>>>(aeh, ael, kah, y, nullptr, nullptr, nullptr, nullptr, e_buf);
    scan16_kernel<1><<<32, 512, 0, stream>>>(mh, ml, nullptr, nullptr, e_buf, nullptr, nullptr, nullptr, e2);
    scan16_kernel<2><<<4, 512, 0, stream>>>(m2h, m2l, nullptr, nullptr, e2, nullptr, nullptr, c2, nullptr);
    scan16_kernel<3><<<32, 512, 0, stream>>>(mh, ml, nullptr, nullptr, e_buf, c2, nullptr, cbuf, nullptr);
    scan16_kernel<4><<<256, 512, 0, stream>>>(aeh, ael, kah, y, nullptr, cbuf, out, nullptr, nullptr);
}

// Round 10
// 255.959 us; speedup vs baseline: 1.0145x; 1.0145x over previous
//
#include <hip/hip_runtime.h>
#include <hip/hip_bf16.h>

#define NS 256    // n_state
#define MO 128    // n_obs
#define BB 64     // batch
#define TT 1024   // time steps

typedef short s16x8 __attribute__((ext_vector_type(8)));
typedef float f32x4 __attribute__((ext_vector_type(4)));
typedef unsigned int uint;
typedef unsigned short ushort;

__device__ __forceinline__ ushort f2bf(float x) {
    uint u = __float_as_uint(x);
    uint r = (u + 0x7fffu + ((u >> 16) & 1u)) >> 16;
    return (ushort)r;
}
__device__ __forceinline__ float bf2f(ushort h) { return __uint_as_float(((uint)h) << 16); }

__device__ __forceinline__ uint pkbf2(float a, float b) {
    __hip_bfloat162 h = __float22bfloat162_rn(make_float2(a, b));
    union { __hip_bfloat162 b2; uint u; } cv;
    cv.b2 = h;
    return cv.u;
}

// split 8 fp32 into bf16 hi + lo fragments (element order = k ascending)
__device__ __forceinline__ void conv8(float4 f0, float4 f1, s16x8& vh, s16x8& vl) {
    uint h0 = pkbf2(f0.x, f0.y), h1 = pkbf2(f0.z, f0.w);
    uint h2 = pkbf2(f1.x, f1.y), h3 = pkbf2(f1.z, f1.w);
    float r0 = f0.x - __uint_as_float(h0 << 16);
    float r1 = f0.y - __uint_as_float(h0 & 0xffff0000u);
    float r2 = f0.z - __uint_as_float(h1 << 16);
    float r3 = f0.w - __uint_as_float(h1 & 0xffff0000u);
    float r4 = f1.x - __uint_as_float(h2 << 16);
    float r5 = f1.y - __uint_as_float(h2 & 0xffff0000u);
    float r6 = f1.z - __uint_as_float(h3 << 16);
    float r7 = f1.w - __uint_as_float(h3 & 0xffff0000u);
    uint l0 = pkbf2(r0, r1), l1 = pkbf2(r2, r3);
    uint l2 = pkbf2(r4, r5), l3 = pkbf2(r6, r7);
    union { uint u[4]; s16x8 v; } ch, cl;
    ch.u[0] = h0; ch.u[1] = h1; ch.u[2] = h2; ch.u[3] = h3;
    cl.u[0] = l0; cl.u[1] = l1; cl.u[2] = l2; cl.u[3] = l3;
    vh = ch.v; vl = cl.v;
}

__device__ __forceinline__ f32x4 mfma16(s16x8 a, s16x8 b, f32x4 c) {
    return __builtin_amdgcn_mfma_f32_16x16x32_bf16(a, b, c, 0, 0, 0);
}

// ---------------- setup kernels ----------------

// Fused: KH row i; AE[i][:] = A[i][:] - KH_row @ A; emit kah (K hi), aeh/ael.
__global__ void khaeff_kernel(const float* __restrict__ K, const float* __restrict__ H,
                              const float* __restrict__ A, float* __restrict__ AE,
                              ushort* __restrict__ kah,
                              ushort* __restrict__ aeh, ushort* __restrict__ ael) {
    int i = blockIdx.x, j = threadIdx.x;
    __shared__ float kl[MO];
    __shared__ float khr[NS];
    if (j < MO) {
        float v = K[i * MO + j];
        kl[j] = v;
        kah[i * MO + j] = f2bf(v);
    }
    __syncthreads();
    float acc = 0.f;
#pragma unroll 8
    for (int k = 0; k < MO; ++k) acc += kl[k] * H[k * NS + j];
    khr[j] = acc;
    __syncthreads();
    float ae = A[i * NS + j];
#pragma unroll 8
    for (int k = 0; k < NS; ++k) ae -= khr[k] * A[k * NS + j];
    AE[i * NS + j] = ae;
    ushort hi = f2bf(ae);
    aeh[i * NS + j] = hi;
    ael[i * NS + j] = f2bf(ae - bf2f(hi));
}

__global__ void matsq_kernel(const float* __restrict__ src, float* __restrict__ dst,
                             ushort* dh, ushort* dl) {
    int i = blockIdx.x, j = threadIdx.x;
    __shared__ float row[NS];
    row[j] = src[i * NS + j];
    __syncthreads();
    float acc = 0.f;
#pragma unroll 8
    for (int k = 0; k < NS; ++k) acc += row[k] * src[k * NS + j];
    dst[i * NS + j] = acc;
    if (dh) {
        ushort hi = f2bf(acc);
        dh[i * NS + j] = hi;
        dl[i * NS + j] = f2bf(acc - bf2f(hi));
    }
}

// ---------------- transposed MFMA serial scan, fused u = K@y^T ----------------
// D = M·x^T + K·y^T (transposed: M/K are MFMA A-operands, x/y are B-operands).
// x-term uses SIX independent accumulator chains of depth 8 (vs one 24-deep
// chain) to hide dependent-MFMA latency; combined with two f32x4 adds.
// Hierarchy: 1024 = 16(step) x 8(chunk) x 8(group).
// MODE 0: grid 256, S=16, u from y, x0=0, end -> e_buf bf16 [b][64][NS].
// MODE 1: grid 32,  S=8,  u=e_buf[b][8g+s], x0=0, end -> e2 bf16 [b][8][NS].
// MODE 2: grid 4,   S=7,  u=e2[b][s], A^128, writes c2[b][s+1], c2[b][0]=0.
// MODE 3: grid 32,  S=7,  u=e_buf[b][8g+s], x0=c2[b][g], writes cbuf[b][8g+s+1],
//                          cbuf[b][8g]=x0.
// MODE 4: grid 256, S=16, u from y, x0=cbuf[b][cc], writes out (float4 direct).

template <int MODE>
__launch_bounds__(512, 1)
__global__ void scan16_kernel(const ushort* __restrict__ mh, const ushort* __restrict__ ml,
                              const ushort* __restrict__ kah,
                              const float* __restrict__ y_g, const ushort* __restrict__ ub,
                              const ushort* __restrict__ cin, float* outf,
                              ushort* __restrict__ wbf, ushort* __restrict__ ebf) {
    constexpr bool YF = (MODE == 0 || MODE == 4);
    constexpr int S = YF ? 16 : ((MODE == 1) ? 8 : 7);
    const int tid = threadIdx.x, blk = blockIdx.x;
    const int w = tid >> 6, l = tid & 63, lr = l & 15, lg = l >> 4;

    __shared__ ushort xh_s[2][16 * NS];
    __shared__ ushort xl_s[2][16 * NS];

    // matrix A-fragments (bf16 hi/lo): lane holds M[32w+16t+lr][32q+8lg..+7]
    s16x8 Bh[2][8], Bl[2][8];
#pragma unroll
    for (int t2 = 0; t2 < 2; ++t2) {
        int row = 16 * (2 * w + t2) + lr;
#pragma unroll
        for (int q = 0; q < 8; ++q) {
            int off = row * NS + 32 * q + 8 * lg;
            Bh[t2][q] = *(const s16x8*)(mh + off);
            Bl[t2][q] = *(const s16x8*)(ml + off);
        }
    }

    // K hi A-fragments (fused modes only)
    s16x8 KAh[2][4];
    if constexpr (YF) {
#pragma unroll
        for (int t2 = 0; t2 < 2; ++t2) {
            int row = 16 * (2 * w + t2) + lr;
#pragma unroll
            for (int q = 0; q < 4; ++q) {
                KAh[t2][q] = *(const s16x8*)(kah + row * MO + 32 * q + 8 * lg);
            }
        }
    }

    const int b0 = (blk & 3) * 16;   // modes 0/4
    const int cc = blk >> 2;         // modes 0/4 (0..63)

    // ---- init x state (buffer 0) + mode-specific init writes ----
#pragma unroll
    for (int jj = 0; jj < 8; ++jj) {
        int idx = jj * 512 + tid;  // 0..4095
        int m = idx >> 8, col = idx & 255;  // m = batch-column of tile
        ushort hu = 0;
        if constexpr (MODE == 3) {
            int rid = blk * 16 + m;
            int b = rid >> 3, g = rid & 7;
            hu = cin[((long)b * 8 + g) * NS + col];
            wbf[((long)b * 64 + 8 * g) * NS + col] = hu;  // cbuf[b][8g] = carry
        } else if constexpr (MODE == 4) {
            hu = cin[((long)(b0 + m) * 64 + cc) * NS + col];
        } else if constexpr (MODE == 2) {
            wbf[(long)(blk * 16 + m) * 8 * NS + col] = 0;  // c2[b][0] = 0
        }
        int si = (m * NS + col) ^ ((m & 7) << 3);
        xh_s[0][si] = hu;
        xl_s[0][si] = 0;
    }

    // state-column bases for this thread's two output tiles
    const int st0 = 32 * w + 4 * lg;
    const int st1 = st0 + 16;

    // y base (fused) / u base (bf16 carry modes)
    long ybase = 0, ubase = 0;
    if constexpr (YF) {
        ybase = ((long)(b0 + lr) * TT + cc * 16) * MO + 8 * lg;
    } else if constexpr (MODE == 1 || MODE == 3) {
        int rid = blk * 16 + lr;
        ubase = ((long)(rid >> 3) * 64 + 8 * (rid & 7)) * NS;
    } else {
        ubase = (long)(blk * 16 + lr) * 8 * NS;
    }

    auto ldu = [&](long off) -> f32x4 {
        uint2 v = *(const uint2*)(ub + off);
        return f32x4{__uint_as_float(v.x << 16), __uint_as_float(v.x & 0xffff0000u),
                     __uint_as_float(v.y << 16), __uint_as_float(v.y & 0xffff0000u)};
    };

    float4 yraw[8];
    auto load_y = [&](int s) {
#pragma unroll
        for (int q = 0; q < 4; ++q) {
            long off = ybase + (long)s * MO + 32 * q;
            yraw[2 * q] = *(const float4*)(y_g + off);
            yraw[2 * q + 1] = *(const float4*)(y_g + off + 4);
        }
    };

    // u(s) from yraw: u = K_hi·(y_hi + y_lo), 16 MFMAs (has a full step of slack)
    auto compute_u = [&](f32x4& ua0, f32x4& ua1) {
        ua0 = f32x4{0.f, 0.f, 0.f, 0.f};
        ua1 = f32x4{0.f, 0.f, 0.f, 0.f};
#pragma unroll
        for (int q = 0; q < 4; ++q) {
            s16x8 yh, yl;
            conv8(yraw[2 * q], yraw[2 * q + 1], yh, yl);
            ua0 = mfma16(KAh[0][q], yh, ua0);
            ua0 = mfma16(KAh[0][q], yl, ua0);
            ua1 = mfma16(KAh[1][q], yh, ua1);
            ua1 = mfma16(KAh[1][q], yl, ua1);
        }
    };

    f32x4 up0, up1;
    if constexpr (YF) {
        load_y(0);
        compute_u(up0, up1);
    } else {
        up0 = ldu(ubase + st0);
        up1 = ldu(ubase + st1);
    }
    __syncthreads();

    for (int s = 0; s < S; ++s) {
        const int cur = s & 1, nxt = cur ^ 1;

        // issue raw y loads for s+1 FIRST (latency covered by the x-chain)
        if constexpr (YF) {
            if (s + 1 < S) load_y(s + 1);
        }

        // serial x-chain as SIX independent depth-8 accumulator chains
        f32x4 a0a = up0, a0b = {0.f, 0.f, 0.f, 0.f}, a0c = {0.f, 0.f, 0.f, 0.f};
        f32x4 a1a = up1, a1b = {0.f, 0.f, 0.f, 0.f}, a1c = {0.f, 0.f, 0.f, 0.f};
#pragma unroll
        for (int q = 0; q < 8; ++q) {
            int ridx = (lr * NS + 32 * q + 8 * lg) ^ ((lr & 7) << 3);
            s16x8 xh = *(const s16x8*)&xh_s[cur][ridx];
            s16x8 xl = *(const s16x8*)&xl_s[cur][ridx];
            a0a = mfma16(Bh[0][q], xh, a0a);
            a0b = mfma16(Bh[0][q], xl, a0b);
            a0c = mfma16(Bl[0][q], xh, a0c);
            a1a = mfma16(Bh[1][q], xh, a1a);
            a1b = mfma16(Bh[1][q], xl, a1b);
            a1c = mfma16(Bl[1][q], xh, a1c);
        }
        f32x4 acc0 = (a0a + a0b) + a0c;
        f32x4 acc1 = (a1a + a1b) + a1c;

        // u for next step (off the critical chain; y already in regs)
        if (s + 1 < S) {
            if constexpr (YF) {
                compute_u(up0, up1);
            } else {
                up0 = ldu(ubase + (long)(s + 1) * NS + st0);
                up1 = ldu(ubase + (long)(s + 1) * NS + st1);
            }
        }

        // packed bf16 of results (hi)
        uint h01a = pkbf2(acc0[0], acc0[1]), h23a = pkbf2(acc0[2], acc0[3]);
        uint h01b = pkbf2(acc1[0], acc1[1]), h23b = pkbf2(acc1[2], acc1[3]);

        // mode-specific global stores
        if constexpr (MODE == 2) {
            long wb = ((long)(blk * 16 + lr) * 8 + s + 1) * NS;
            *(uint2*)(wbf + wb + st0) = make_uint2(h01a, h23a);
            *(uint2*)(wbf + wb + st1) = make_uint2(h01b, h23b);
        } else if constexpr (MODE == 3) {
            int rid = blk * 16 + lr;
            long wb = ((long)(rid >> 3) * 64 + 8 * (rid & 7) + s + 1) * NS;
            *(uint2*)(wbf + wb + st0) = make_uint2(h01a, h23a);
            *(uint2*)(wbf + wb + st1) = make_uint2(h01b, h23b);
        } else if constexpr (MODE == 4) {
            long ob = ((long)(b0 + lr) * TT + cc * 16 + s) * NS;
            *(f32x4*)(outf + ob + st0) = acc0;
            *(f32x4*)(outf + ob + st1) = acc1;
        } else if constexpr (MODE == 0) {
            if (s == S - 1) {
                long eb = ((long)(b0 + lr) * 64 + cc) * NS;
                *(uint2*)(ebf + eb + st0) = make_uint2(h01a, h23a);
                *(uint2*)(ebf + eb + st1) = make_uint2(h01b, h23b);
            }
        } else if constexpr (MODE == 1) {
            if (s == S - 1) {
                int rid = blk * 16 + lr;
                long eb = ((long)(rid >> 3) * 8 + (rid & 7)) * NS;
                *(uint2*)(ebf + eb + st0) = make_uint2(h01a, h23a);
                *(uint2*)(ebf + eb + st1) = make_uint2(h01b, h23b);
            }
        }

        // write x[nxt]: vector b64 LDS writes under the (lr&7)<<3 XOR
        if (s + 1 < S) {
            float la0 = acc0[0] - __uint_as_float(h01a << 16);
            float la1 = acc0[1] - __uint_as_float(h01a & 0xffff0000u);
            float la2 = acc0[2] - __uint_as_float(h23a << 16);
            float la3 = acc0[3] - __uint_as_float(h23a & 0xffff0000u);
            float lb0 = acc1[0] - __uint_as_float(h01b << 16);
            float lb1 = acc1[1] - __uint_as_float(h01b & 0xffff0000u);
            float lb2 = acc1[2] - __uint_as_float(h23b << 16);
            float lb3 = acc1[3] - __uint_as_float(h23b & 0xffff0000u);
            int wi0 = lr * NS + (st0 ^ ((lr & 7) << 3));
            int wi1 = lr * NS + (st1 ^ ((lr & 7) << 3));
            *(uint2*)&xh_s[nxt][wi0] = make_uint2(h01a, h23a);
            *(uint2*)&xh_s[nxt][wi1] = make_uint2(h01b, h23b);
            *(uint2*)&xl_s[nxt][wi0] = make_uint2(pkbf2(la0, la1), pkbf2(la2, la3));
            *(uint2*)&xl_s[nxt][wi1] = make_uint2(pkbf2(lb0, lb1), pkbf2(lb2, lb3));
        }
        __syncthreads();
    }
}

// ---------------- launcher ----------------

extern "C" void kernel_launch(void* const* d_in, const int* in_sizes, int n_in,
                              void* d_out, int out_size, void* d_ws, size_t ws_size,
                              hipStream_t stream) {
    const float* y = (const float*)d_in[0];
    const float* A = (const float*)d_in[1];
    const float* H = (const float*)d_in[2];
    const float* K = (const float*)d_in[3];
    float* out = (float*)d_out;

    float* ws = (float*)d_ws;
    const long MAT = (long)NS * NS;  // 65536
    float* AE = ws + 0 * MAT;
    float* Ta = ws + 1 * MAT;
    float* Tb = ws + 2 * MAT;
    ushort* us = (ushort*)(ws + 3 * MAT);
    ushort* aeh = us;                       // 65536
    ushort* ael = aeh + MAT;                // 65536
    ushort* mh = ael + MAT;                 // A^16 hi
    ushort* ml = mh + MAT;
    ushort* m2h = ml + MAT;                 // A^128 hi
    ushort* m2l = m2h + MAT;
    ushort* kah = m2l + MAT;                // K hi: 32768
    ushort* e_buf = kah + (long)NS * MO;    // [64][64][256] = 1,048,576
    ushort* cbuf = e_buf + (long)BB * 64 * NS;
    ushort* e2 = cbuf + (long)BB * 64 * NS; // [64][8][256] = 131,072
    ushort* c2 = e2 + (long)BB * 8 * NS;

    khaeff_kernel<<<NS, NS, 0, stream>>>(K, H, A, AE, kah, aeh, ael);
    matsq_kernel<<<NS, NS, 0, stream>>>(AE, Ta, nullptr, nullptr);   // A^2
    matsq_kernel<<<NS, NS, 0, stream>>>(Ta, Tb, nullptr, nullptr);   // A^4
    matsq_kernel<<<NS, NS, 0, stream>>>(Tb, Ta, nullptr, nullptr);   // A^8
    matsq_kernel<<<NS, NS, 0, stream>>>(Ta, Tb, mh, ml);             // A^16 (+conv)
    matsq_kernel<<<NS, NS, 0, stream>>>(Tb, Ta, nullptr, nullptr);   // A^32
    matsq_kernel<<<NS, NS, 0, stream>>>(Ta, Tb, nullptr, nullptr);   // A^64
    matsq_kernel<<<NS, NS, 0, stream>>>(Tb, Ta, m2h, m2l);           // A^128 (+conv)

    scan16_kernel<0><<<256, 512, 0, stream>>>(aeh, ael, kah, y, nullptr, nullptr, nullptr, nullptr, e_buf);
    scan16_kernel<1><<<32, 512, 0, stream>>>(mh, ml, nullptr, nullptr, e_buf, nullptr, nullptr, nullptr, e2);
    scan16_kernel<2><<<4, 512, 0, stream>>>(m2h, m2l, nullptr, nullptr, e2, nullptr, nullptr, c2, nullptr);
    scan16_kernel<3><<<32, 512, 0, stream>>>(mh, ml, nullptr, nullptr, e_buf, c2, nullptr, cbuf, nullptr);
    scan16_kernel<4><<<256, 512, 0, stream>>>(aeh, ael, kah, y, nullptr, cbuf, out, nullptr, nullptr);
}